// Round 1
// 311.061 us; speedup vs baseline: 1.0790x; 1.0790x over previous
//
#include <hip/hip_runtime.h>

#define D_IN 512
#define D_OUT 256
#define BM 64     // gemm M-tile (BN = full D_OUT = 256)
#define BK 32
#define LDK 40    // padded LDS row stride (elems): 80 B, 16B-aligned rows, ~2-way bank alias

typedef short short8 __attribute__((ext_vector_type(8)));
typedef float floatx4 __attribute__((ext_vector_type(4)));

static __device__ __forceinline__ unsigned short f2bf(float f) {
    unsigned u = __float_as_uint(f);
    u += 0x7FFF + ((u >> 16) & 1);
    return (unsigned short)(u >> 16);
}
static __device__ __forceinline__ float bf2f(unsigned short h) {
    return __uint_as_float((unsigned)h << 16);
}

// ---------------- fused: W convert+transpose + cnt zeroing ----------------
// blocks [0, 256): Wt[n][k] = bf16(W[k][n]);  blocks [256, ...): cnt[i] = 0
#define CONV_BLOCKS 256
__global__ __launch_bounds__(512) void convert_and_zero(const float* __restrict__ W,
                                                        unsigned short* __restrict__ Wt,
                                                        int* __restrict__ cnt, int M) {
    int b = blockIdx.x;
    if (b < CONV_BLOCKS) {
        int t = b * 512 + threadIdx.x;     // D_IN*D_OUT = 131072 = 256*512
        int n = t >> 9;
        int k = t & 511;
        Wt[t] = f2bf(W[(size_t)k * D_OUT + n]);
    } else {
        int i = (b - CONV_BLOCKS) * 512 + threadIdx.x;
        if (i < M) cnt[i] = 0;
    }
}

// ---------------- CSR build: histogram + 3-phase scan ----------------
__global__ __launch_bounds__(256) void hist_rows(const int* __restrict__ rows,
                                                 int* __restrict__ cnt, int E) {
    int e = blockIdx.x * 256 + threadIdx.x;
    if (e < E) atomicAdd(&cnt[rows[e]], 1);
}

#define SCAN_B 4096
__global__ __launch_bounds__(1024) void scan_blocks(const int* __restrict__ cnt,
                                                    int* __restrict__ ptr,
                                                    int* __restrict__ partials, int M) {
    __shared__ int wsum[16];
    const int t = threadIdx.x, lane = t & 63, wave = t >> 6;
    const int base = blockIdx.x * SCAN_B + t * 4;
    int4 v = make_int4(0, 0, 0, 0);
    if (base + 3 < M) v = *(const int4*)(cnt + base);
    else {
        if (base + 0 < M) v.x = cnt[base + 0];
        if (base + 1 < M) v.y = cnt[base + 1];
        if (base + 2 < M) v.z = cnt[base + 2];
        if (base + 3 < M) v.w = cnt[base + 3];
    }
    int s = v.x + v.y + v.z + v.w;
    int incl = s;
#pragma unroll
    for (int off = 1; off < 64; off <<= 1) {
        int x = __shfl_up(incl, off, 64);
        if (lane >= off) incl += x;
    }
    if (lane == 63) wsum[wave] = incl;
    __syncthreads();
    if (t == 0) {
        int run = 0;
#pragma unroll
        for (int w = 0; w < 16; ++w) { int x = wsum[w]; wsum[w] = run; run += x; }
        partials[blockIdx.x] = run;
    }
    __syncthreads();
    int e0 = wsum[wave] + (incl - s);
    int e1 = e0 + v.x, e2 = e1 + v.y, e3 = e2 + v.z;
    if (base + 3 < M) *(int4*)(ptr + base) = make_int4(e0, e1, e2, e3);
    else {
        if (base + 0 < M) ptr[base + 0] = e0;
        if (base + 1 < M) ptr[base + 1] = e1;
        if (base + 2 < M) ptr[base + 2] = e2;
        if (base + 3 < M) ptr[base + 3] = e3;
    }
}

__global__ __launch_bounds__(64) void scan_partials(int* __restrict__ partials,
                                                    int* __restrict__ ptr, int M, int nb) {
    const int t = threadIdx.x;
    int v = (t < nb) ? partials[t] : 0;
    int incl = v;
#pragma unroll
    for (int off = 1; off < 64; off <<= 1) {
        int x = __shfl_up(incl, off, 64);
        if (t >= off) incl += x;
    }
    if (t < nb) partials[t] = incl - v;
    if (t == 63) ptr[M] = incl;
}

__global__ __launch_bounds__(256) void add_offsets(int* __restrict__ ptr,
                                                   const int* __restrict__ partials,
                                                   int M) {
    int i = blockIdx.x * 256 + threadIdx.x;
    if (i < M) ptr[i] += partials[i >> 12];   // SCAN_B = 4096 = 1<<12
}

// ---------------- fused GEMM (blocks [0,nGemm)) + edge placement (rest) ----------------
// GEMM: S(bf16) = bf16(A) @ bf16(W), fp32 accum. BM=64 x BN=256, 8 waves,
// wave tile 64x32, register-prefetch pipeline. A is read from HBM exactly once;
// Wt re-reads (256 KB) are L2 hits.
// Build: destructive CSR placement — atomicAdd on ptr; afterwards ptr[r] = start[r+1].
__global__ __launch_bounds__(512, 4) void gemm_build(
    const float* __restrict__ A, const unsigned short* __restrict__ Wt,
    unsigned short* __restrict__ S, int M, int nGemm,
    const float* __restrict__ vals, const int* __restrict__ rows,
    const int* __restrict__ cols, int* __restrict__ ptr,
    int2* __restrict__ edges, int E) {
    __shared__ unsigned short As[BM * LDK];      // 5.0 KB
    __shared__ unsigned short Bs[D_OUT * LDK];   // 20.0 KB
    const int tid = threadIdx.x;

    if ((int)blockIdx.x >= nGemm) {
        // ---- build role: 512 edges per block ----
        int e = ((int)blockIdx.x - nGemm) * 512 + tid;
        if (e < E) {
            int r = rows[e];
            int pos = atomicAdd(&ptr[r], 1);
            edges[pos] = make_int2(cols[e], __float_as_int(vals[e]));
        }
        return;
    }

    // ---- gemm role ----
    const int lane = tid & 63;
    const int wave = tid >> 6;
    const int wn   = wave * 32;                  // 8 waves cover 256 cols
    const int bm   = blockIdx.x * BM;
    const int l15  = lane & 15;
    const int quad = lane >> 4;

    // A staging: 1 item/thread (64 rows x 8 segments of 4 floats)
    const int am   = tid >> 3;
    const int ak4  = (tid & 7) * 4;
    const bool aval = (bm + am) < M;
    const float* aptr = A + (size_t)(aval ? bm + am : 0) * D_IN + ak4;
    const int aoff = am * LDK + ak4;

    // B staging: 2 items/thread (256 rows x 4 segments of 8 bf16)
    const unsigned short* bptr[2];
    int boff[2];
#pragma unroll
    for (int i = 0; i < 2; ++i) {
        int item = tid + i * 512;                // 0..1023
        int bn = item >> 2;                      // 0..255
        int k8 = (item & 3) * 8;                 // 0,8,16,24
        bptr[i] = Wt + (size_t)bn * D_IN + k8;
        boff[i] = bn * LDK + k8;
    }

    // prologue: load K-tile 0 into registers
    float4 aR = aval ? *(const float4*)aptr : make_float4(0.f, 0.f, 0.f, 0.f);
    short8 bR[2];
#pragma unroll
    for (int i = 0; i < 2; ++i) bR[i] = *(const short8*)(bptr[i]);

    floatx4 acc[4][2] = {};

    for (int k0 = 0; k0 < D_IN; k0 += BK) {
        // drain staged regs -> LDS (A converted to bf16)
        ushort4 ab;
        ab.x = f2bf(aR.x); ab.y = f2bf(aR.y); ab.z = f2bf(aR.z); ab.w = f2bf(aR.w);
        *(ushort4*)(As + aoff) = ab;
#pragma unroll
        for (int i = 0; i < 2; ++i) *(short8*)(Bs + boff[i]) = bR[i];
        __syncthreads();

        // prefetch next K-tile (overlaps frag reads + MFMA + end barrier)
        if (k0 + BK < D_IN) {
            aR = aval ? *(const float4*)(aptr + k0 + BK)
                      : make_float4(0.f, 0.f, 0.f, 0.f);
#pragma unroll
            for (int i = 0; i < 2; ++i) bR[i] = *(const short8*)(bptr[i] + k0 + BK);
        }

        short8 af[4], bfr[2];
#pragma unroll
        for (int i = 0; i < 4; ++i)
            af[i] = *(const short8*)(As + (i * 16 + l15) * LDK + quad * 8);
#pragma unroll
        for (int j = 0; j < 2; ++j)
            bfr[j] = *(const short8*)(Bs + (wn + j * 16 + l15) * LDK + quad * 8);
#pragma unroll
        for (int i = 0; i < 4; ++i)
#pragma unroll
            for (int j = 0; j < 2; ++j)
                acc[i][j] = __builtin_amdgcn_mfma_f32_16x16x32_bf16(
                    af[i], bfr[j], acc[i][j], 0, 0, 0);
        __syncthreads();
    }

    // epilogue: row = bm+i*16+quad*4+r, col = wn+j*16+l15
#pragma unroll
    for (int i = 0; i < 4; ++i) {
#pragma unroll
        for (int r = 0; r < 4; ++r) {
            int gm = bm + i * 16 + quad * 4 + r;
            if (gm < M) {
#pragma unroll
                for (int j = 0; j < 2; ++j)
                    S[(size_t)gm * D_OUT + wn + j * 16 + l15] = f2bf(acc[i][j][r]);
            }
        }
    }
}

// ---------------- Aggregate: one wave/row, 8-edge unroll, fp32 accum ----------------
// Reads shifted (destructive) CSR: row extent = [row ? ptr[row-1] : 0, ptr[row]).
__global__ __launch_bounds__(256) void spmm_rows(const unsigned short* __restrict__ S,
                                                 const int2* __restrict__ edges,
                                                 const int* __restrict__ ptr,
                                                 const float* __restrict__ bias,
                                                 float* __restrict__ out, int M) {
    const int row = blockIdx.x * 4 + (threadIdx.x >> 6);
    if (row >= M) return;
    const int lane = threadIdx.x & 63;
    float4 a0 = ((const float4*)bias)[lane];
    float4 a1 = make_float4(0.f, 0.f, 0.f, 0.f);
    const int beg = row ? ptr[row - 1] : 0;
    const int end = ptr[row];
    int j = beg;
    for (; j + 7 < end; j += 8) {
        int2 e0 = edges[j + 0], e1 = edges[j + 1], e2 = edges[j + 2], e3 = edges[j + 3];
        int2 e4 = edges[j + 4], e5 = edges[j + 5], e6 = edges[j + 6], e7 = edges[j + 7];
        ushort4 s0 = ((const ushort4*)(S + (size_t)e0.x * D_OUT))[lane];
        ushort4 s1 = ((const ushort4*)(S + (size_t)e1.x * D_OUT))[lane];
        ushort4 s2 = ((const ushort4*)(S + (size_t)e2.x * D_OUT))[lane];
        ushort4 s3 = ((const ushort4*)(S + (size_t)e3.x * D_OUT))[lane];
        ushort4 s4 = ((const ushort4*)(S + (size_t)e4.x * D_OUT))[lane];
        ushort4 s5 = ((const ushort4*)(S + (size_t)e5.x * D_OUT))[lane];
        ushort4 s6 = ((const ushort4*)(S + (size_t)e6.x * D_OUT))[lane];
        ushort4 s7 = ((const ushort4*)(S + (size_t)e7.x * D_OUT))[lane];
        float v0 = __int_as_float(e0.y), v1 = __int_as_float(e1.y);
        float v2 = __int_as_float(e2.y), v3 = __int_as_float(e3.y);
        float v4 = __int_as_float(e4.y), v5 = __int_as_float(e5.y);
        float v6 = __int_as_float(e6.y), v7 = __int_as_float(e7.y);
        a0.x += v0 * bf2f(s0.x) + v2 * bf2f(s2.x) + v4 * bf2f(s4.x) + v6 * bf2f(s6.x);
        a0.y += v0 * bf2f(s0.y) + v2 * bf2f(s2.y) + v4 * bf2f(s4.y) + v6 * bf2f(s6.y);
        a0.z += v0 * bf2f(s0.z) + v2 * bf2f(s2.z) + v4 * bf2f(s4.z) + v6 * bf2f(s6.z);
        a0.w += v0 * bf2f(s0.w) + v2 * bf2f(s2.w) + v4 * bf2f(s4.w) + v6 * bf2f(s6.w);
        a1.x += v1 * bf2f(s1.x) + v3 * bf2f(s3.x) + v5 * bf2f(s5.x) + v7 * bf2f(s7.x);
        a1.y += v1 * bf2f(s1.y) + v3 * bf2f(s3.y) + v5 * bf2f(s5.y) + v7 * bf2f(s7.y);
        a1.z += v1 * bf2f(s1.z) + v3 * bf2f(s3.z) + v5 * bf2f(s5.z) + v7 * bf2f(s7.z);
        a1.w += v1 * bf2f(s1.w) + v3 * bf2f(s3.w) + v5 * bf2f(s5.w) + v7 * bf2f(s7.w);
    }
    for (; j + 3 < end; j += 4) {
        int2 e0 = edges[j], e1 = edges[j + 1], e2 = edges[j + 2], e3 = edges[j + 3];
        ushort4 s0 = ((const ushort4*)(S + (size_t)e0.x * D_OUT))[lane];
        ushort4 s1 = ((const ushort4*)(S + (size_t)e1.x * D_OUT))[lane];
        ushort4 s2 = ((const ushort4*)(S + (size_t)e2.x * D_OUT))[lane];
        ushort4 s3 = ((const ushort4*)(S + (size_t)e3.x * D_OUT))[lane];
        float v0 = __int_as_float(e0.y), v1 = __int_as_float(e1.y);
        float v2 = __int_as_float(e2.y), v3 = __int_as_float(e3.y);
        a0.x += v0 * bf2f(s0.x) + v2 * bf2f(s2.x);
        a0.y += v0 * bf2f(s0.y) + v2 * bf2f(s2.y);
        a0.z += v0 * bf2f(s0.z) + v2 * bf2f(s2.z);
        a0.w += v0 * bf2f(s0.w) + v2 * bf2f(s2.w);
        a1.x += v1 * bf2f(s1.x) + v3 * bf2f(s3.x);
        a1.y += v1 * bf2f(s1.y) + v3 * bf2f(s3.y);
        a1.z += v1 * bf2f(s1.z) + v3 * bf2f(s3.z);
        a1.w += v1 * bf2f(s1.w) + v3 * bf2f(s3.w);
    }
    for (; j < end; ++j) {
        int2 e = edges[j];
        float v = __int_as_float(e.y);
        ushort4 s = ((const ushort4*)(S + (size_t)e.x * D_OUT))[lane];
        a0.x += v * bf2f(s.x);
        a0.y += v * bf2f(s.y);
        a0.z += v * bf2f(s.z);
        a0.w += v * bf2f(s.w);
    }
    a0.x += a1.x; a0.y += a1.y; a0.z += a1.z; a0.w += a1.w;
    // out is never re-read: non-temporal store keeps S resident in L2
    floatx4 res = {a0.x, a0.y, a0.z, a0.w};
    __builtin_nontemporal_store(res, (floatx4*)(out + (size_t)row * D_OUT) + lane);
}

extern "C" void kernel_launch(void* const* d_in, const int* in_sizes, int n_in,
                              void* d_out, int out_size, void* d_ws, size_t ws_size,
                              hipStream_t stream) {
    const float* inputs    = (const float*)d_in[0];
    const float* weights   = (const float*)d_in[1];
    const float* bias      = (const float*)d_in[2];
    const float* edge_vals = (const float*)d_in[3];
    const int*   edge_row  = (const int*)d_in[4];
    const int*   edge_col  = (const int*)d_in[5];
    float* out = (float*)d_out;

    const int M = in_sizes[0] / D_IN;  // 50000
    const int E = in_sizes[3];         // 800000

    // Workspace (all chunk sizes multiples of 16 B):
    //   S: M*D_OUT bf16 | Wt: D_OUT*D_IN bf16 | edges: E int2 | ptr: M+1 | cnt: M | partials
    char* ws = (char*)d_ws;
    unsigned short* S  = (unsigned short*)ws;
    unsigned short* Wt = (unsigned short*)(ws + (size_t)M * D_OUT * 2);
    int2* edges        = (int2*)((char*)Wt + (size_t)D_OUT * D_IN * 2);
    int*  ptr          = (int*)((char*)edges + (size_t)E * 8);
    int*  cnt          = ptr + ((M + 4) & ~3);
    int*  partials     = cnt + M;

    // 1) W -> bf16 transposed, fused with cnt zeroing
    int nzero = (M + 511) / 512;
    convert_and_zero<<<CONV_BLOCKS + nzero, 512, 0, stream>>>(weights, Wt, cnt, M);

    // 2) CSR histogram + scan (tiny)
    hist_rows<<<(E + 255) / 256, 256, 0, stream>>>(edge_row, cnt, E);
    int nb = (M + SCAN_B - 1) / SCAN_B;   // 13
    scan_blocks<<<nb, 1024, 0, stream>>>(cnt, ptr, partials, M);
    scan_partials<<<1, 64, 0, stream>>>(partials, ptr, M, nb);
    add_offsets<<<(M + 255) / 256, 256, 0, stream>>>(ptr, partials, M);

    // 3) GEMM overlapped with destructive edge placement (independent work)
    int nGemm  = (M + BM - 1) / BM;       // 782
    int nBuild = (E + 511) / 512;         // 1563
    gemm_build<<<nGemm + nBuild, 512, 0, stream>>>(inputs, Wt, S, M, nGemm,
                                                   edge_vals, edge_row, edge_col,
                                                   ptr, edges, E);

    // 4) aggregate (shifted CSR bounds)
    spmm_rows<<<(M + 3) / 4, 256, 0, stream>>>(S, edges, ptr, bias, out, M);
}